// Round 7
// baseline (273.929 us; speedup 1.0000x reference)
//
#include <hip/hip_runtime.h>

#define N_NODES 100000
#define N_EDGES 1000000
#define D_IN    256
#define D_OUT   64

// bucket decomposition: 256 nodes per bucket
#define BKT_SHIFT   8
#define NODES_PER_B 256
#define N_BKT       391            // ceil(100000 / 256)
#define BKT_CAP     3072           // mean 2558, sigma ~51 -> +10 sigma slack
#define EPB         8192           // edges per binning block
#define BIN_BLOCKS  123            // ceil(1e6 / 8192)
#define GEMM_BLOCKS 782            // 3128 waves, 2 tiles/wave, 6250 tiles exact
#define NUM_TILES   6250           // 100000 / 16 exactly

typedef __attribute__((ext_vector_type(8))) short short8;
typedef __attribute__((ext_vector_type(4))) float f32x4;

__device__ __forceinline__ unsigned short f2bf(float f) {
    unsigned int u = __float_as_uint(f);
    u = (u + 0x7fffu + ((u >> 16) & 1u)) >> 16;
    return (unsigned short)u;
}
__device__ __forceinline__ float bf2f(unsigned short h) {
    return __uint_as_float((unsigned)h << 16);
}

// wT pad = 264 shorts = 132 dwords = 4 (mod 32) banks/row: the wave's b128
// reads tile all 32 banks exactly 8x -> minimal (conflict-free). [r5/r6 A/B]
__device__ __forceinline__ void mfma_store_tile(
    const short8 afrag[8], const unsigned short wT[64][264],
    unsigned short* __restrict__ hiddenBf, int r0, int n16, int quad)
{
    f32x4 acc[4] = {{0.f,0.f,0.f,0.f},{0.f,0.f,0.f,0.f},
                    {0.f,0.f,0.f,0.f},{0.f,0.f,0.f,0.f}};
#pragma unroll
    for (int ct = 0; ct < 4; ++ct) {
#pragma unroll
        for (int kk = 0; kk < 8; ++kk) {
            short8 b = *(const short8*)&wT[ct * 16 + n16][kk * 32 + quad * 8];
            acc[ct] = __builtin_amdgcn_mfma_f32_16x16x32_bf16(
                afrag[kk], b, acc[ct], 0, 0, 0);
        }
    }
    // C/D layout: col = lane&15, row = quad*4 + reg  [m89-verified]
#pragma unroll
    for (int ct = 0; ct < 4; ++ct)
#pragma unroll
        for (int reg = 0; reg < 4; ++reg)
            hiddenBf[(size_t)(r0 + quad * 4 + reg) * D_OUT + ct * 16 + n16]
                = f2bf(acc[ct][reg]);
}

// ---------------------------------------------------------------------------
// Fused dispatch: blocks [0, BIN_BLOCKS) bin edges into bucket windows;
// remaining blocks run the bf16-MFMA GEMM (2-tile software pipeline).
// ---------------------------------------------------------------------------
__global__ __launch_bounds__(256, 2) void gemm_bin_kernel(
    const float* __restrict__ x, const float* __restrict__ w,
    unsigned short* __restrict__ hiddenBf,
    const int* __restrict__ row, const int* __restrict__ col,
    const float* __restrict__ adj, int* __restrict__ gCursor,
    int2* __restrict__ edges)
{
    const int t = threadIdx.x;

    if (blockIdx.x < BIN_BLOCKS) {
        // ----- bin path -----
        __shared__ int cnt[N_BKT];
        __shared__ int cbase[N_BKT];
        __shared__ int cur[N_BKT];

        const int e0 = blockIdx.x * EPB;

        for (int i = t; i < N_BKT; i += 256) cnt[i] = 0;
        __syncthreads();

        for (int i = t; i < EPB; i += 256) {
            int e = e0 + i;
            if (e < N_EDGES) atomicAdd(&cnt[row[e] >> BKT_SHIFT], 1);
        }
        __syncthreads();

        for (int i = t; i < N_BKT; i += 256) {
            int c = cnt[i];
            cbase[i] = c ? atomicAdd(&gCursor[i], c) : 0;
            cur[i] = 0;
        }
        __syncthreads();

        for (int i = t; i < EPB; i += 256) {
            int e = e0 + i;
            if (e < N_EDGES) {
                int r = row[e];
                int b = r >> BKT_SHIFT;
                int off = cbase[b] + atomicAdd(&cur[b], 1);
                if (off < BKT_CAP) {  // capacity guard (never trips)
                    edges[b * BKT_CAP + off] =
                        make_int2(((r & (NODES_PER_B - 1)) << 17) | col[e],
                                  __float_as_int(adj[e]));
                }
            }
        }
        return;
    }

    // ----- gemm path -----
    __shared__ unsigned short wT[64][264];

    // stage w via float4: 16 independent loads/thread (was 64 serial scalar)
#pragma unroll
    for (int i = 0; i < 16; ++i) {
        int v4 = i * 256 + t;               // float4 index, 0..4095
        float4 f = ((const float4*)w)[v4];
        int k = v4 >> 4;                    // w row (K dim)
        int n = (v4 & 15) * 4;              // w col (N dim), 4 consecutive
        wT[n + 0][k] = f2bf(f.x);
        wT[n + 1][k] = f2bf(f.y);
        wT[n + 2][k] = f2bf(f.z);
        wT[n + 3][k] = f2bf(f.w);
    }
    __syncthreads();

    const int lane = t & 63;
    const int wid  = t >> 6;
    const int n16  = lane & 15;
    const int quad = lane >> 4;

    const int waveGid = (blockIdx.x - BIN_BLOCKS) * 4 + wid;
    const int t0 = waveGid * 2;
    if (t0 >= NUM_TILES) return;

    float4 lo[8], hi[8];
    short8 afrag[8];

    {   // prologue: all 16 loads of tile t0
        const float* xrow = x + (size_t)(t0 * 16 + n16) * D_IN + quad * 8;
#pragma unroll
        for (int kk = 0; kk < 8; ++kk) {
            lo[kk] = *(const float4*)(xrow + kk * 32);
            hi[kk] = *(const float4*)(xrow + kk * 32 + 4);
        }
    }
#pragma unroll
    for (int kk = 0; kk < 8; ++kk) {
        short8 a;
        a[0] = (short)f2bf(lo[kk].x); a[1] = (short)f2bf(lo[kk].y);
        a[2] = (short)f2bf(lo[kk].z); a[3] = (short)f2bf(lo[kk].w);
        a[4] = (short)f2bf(hi[kk].x); a[5] = (short)f2bf(hi[kk].y);
        a[6] = (short)f2bf(hi[kk].z); a[7] = (short)f2bf(hi[kk].w);
        afrag[kk] = a;
    }

    const int t1 = t0 + 1;
    const bool have1 = t1 < NUM_TILES;
    if (have1) {
        const float* xrow = x + (size_t)(t1 * 16 + n16) * D_IN + quad * 8;
#pragma unroll
        for (int kk = 0; kk < 8; ++kk) {
            lo[kk] = *(const float4*)(xrow + kk * 32);
            hi[kk] = *(const float4*)(xrow + kk * 32 + 4);
        }
    }

    mfma_store_tile(afrag, wT, hiddenBf, t0 * 16, n16, quad);

    if (have1) {
#pragma unroll
        for (int kk = 0; kk < 8; ++kk) {
            short8 a;
            a[0] = (short)f2bf(lo[kk].x); a[1] = (short)f2bf(lo[kk].y);
            a[2] = (short)f2bf(lo[kk].z); a[3] = (short)f2bf(lo[kk].w);
            a[4] = (short)f2bf(hi[kk].x); a[5] = (short)f2bf(hi[kk].y);
            a[6] = (short)f2bf(hi[kk].z); a[7] = (short)f2bf(hi[kk].w);
            afrag[kk] = a;
        }
        mfma_store_tile(afrag, wT, hiddenBf, t1 * 16, n16, quad);
    }
}

// ---------------------------------------------------------------------------
// aggsort: one block per bucket. Sort the bucket's edges into node order IN
// LDS (hist + scan + scatter; records stashed in registers between passes —
// the window is read from global exactly once), then 8 waves process 32
// nodes each: records via broadcast ds_read (near-zero latency), 8-deep
// gather pipeline from hiddenBf, fused PReLU. Replaces csr+agg dispatches.
// ---------------------------------------------------------------------------
__global__ __launch_bounds__(512) void aggsort_kernel(
    const unsigned short* __restrict__ hiddenBf,
    const int2* __restrict__ edges, const int* __restrict__ gCursor,
    const float* __restrict__ prelu_a, float* __restrict__ out)
{
    __shared__ int2 srec[BKT_CAP];          // 24576 B, node-sorted records
    __shared__ int  cnt[NODES_PER_B];
    __shared__ int  cur[NODES_PER_B];
    __shared__ unsigned sdp[NODES_PER_B];   // (start<<11)|deg

    const int b = blockIdx.x, t = threadIdx.x;
    if (t < NODES_PER_B) cnt[t] = 0;
    __syncthreads();

    const int base = b * BKT_CAP;
    int size = gCursor[b];
    if (size > BKT_CAP) size = BKT_CAP;

    // pass A: coalesced window read, stash in registers, LDS histogram
    int2 myrec[6];
    int nmine = 0;
    for (int i = t; i < size; i += 512) {
        int2 rec = edges[base + i];
        myrec[nmine++] = rec;
        atomicAdd(&cnt[(unsigned)rec.x >> 17], 1);
    }
    __syncthreads();

    // Hillis-Steele inclusive scan over cnt[256]
    int v = (t < NODES_PER_B) ? cnt[t] : 0;
    for (int off = 1; off < NODES_PER_B; off <<= 1) {
        int tmp = (t < NODES_PER_B && t >= off) ? cnt[t - off] : 0;
        __syncthreads();
        if (t < NODES_PER_B) cnt[t] += tmp;
        __syncthreads();
    }
    if (t < NODES_PER_B) {
        int start = cnt[t] - v;             // exclusive prefix (bucket-local)
        cur[t] = start;
        sdp[t] = ((unsigned)start << 11) | (unsigned)(v < 2047 ? v : 2047);
    }
    __syncthreads();

    // pass B: scatter register stash to node-sorted LDS slots
    for (int j = 0; j < nmine; ++j) {
        int rl  = (unsigned)myrec[j].x >> 17;
        int pos = atomicAdd(&cur[rl], 1);
        srec[pos] = make_int2(myrec[j].x & 0x1FFFF, myrec[j].y);
    }
    __syncthreads();

    // per-wave node processing: wave w -> nodes w, w+8, ..., w+248
    const int wave = t >> 6;
    const int lane = t & 63;
    const float a = prelu_a[0];
    const int node0 = b * NODES_PER_B;

    for (int ni = wave; ni < NODES_PER_B; ni += 8) {
        int node = node0 + ni;
        if (node >= N_NODES) break;         // wave-uniform (last bucket only)
        unsigned sd = sdp[ni];
        int s = sd >> 11;
        int d = sd & 2047;

        float acc = 0.f;
        int j = 0;
        for (; j + 8 <= d; j += 8) {
            float vv[8], hh[8];
#pragma unroll
            for (int u = 0; u < 8; ++u) {
                int2 r = srec[s + j + u];   // uniform addr -> LDS broadcast
                vv[u] = __int_as_float(r.y);
                hh[u] = bf2f(hiddenBf[(size_t)r.x * D_OUT + lane]);
            }
#pragma unroll
            for (int u = 0; u < 8; ++u) acc += vv[u] * hh[u];
        }
        for (; j < d; ++j) {
            int2 r = srec[s + j];
            acc += __int_as_float(r.y) * bf2f(hiddenBf[(size_t)r.x * D_OUT + lane]);
        }
        out[(size_t)node * D_OUT + lane] = acc > 0.f ? acc : a * acc;
    }
}

// ---------------------------------------------------------------------------
extern "C" void kernel_launch(void* const* d_in, const int* in_sizes, int n_in,
                              void* d_out, int out_size, void* d_ws, size_t ws_size,
                              hipStream_t stream)
{
    const float* x       = (const float*)d_in[0];
    const float* w       = (const float*)d_in[1];
    const float* adj     = (const float*)d_in[2];
    const float* prelu_a = (const float*)d_in[3];
    const int*   row     = (const int*)d_in[4];
    const int*   col     = (const int*)d_in[5];
    float* out = (float*)d_out;

    // workspace layout (bytes)
    char* ws = (char*)d_ws;
    unsigned short* hiddenBf = (unsigned short*)(ws);    // 12,800,000
    int2* edges   = (int2*)(ws + 12800000);              //  9,609,216
    int*  gCursor = (int*) (ws + 22409216);              //      1,564

    hipMemsetAsync(gCursor, 0, N_BKT * sizeof(int), stream);

    gemm_bin_kernel<<<BIN_BLOCKS + GEMM_BLOCKS, 256, 0, stream>>>(
        x, w, hiddenBf, row, col, adj, gCursor, edges);

    aggsort_kernel<<<N_BKT, 512, 0, stream>>>(hiddenBf, edges, gCursor, prelu_a, out);
}